// Round 12
// baseline (227.994 us; speedup 1.0000x reference)
//
#include <hip/hip_runtime.h>
#include <math.h>

typedef _Float16 f16;
typedef _Float16 f16x8 __attribute__((ext_vector_type(8)));
typedef float f32x16 __attribute__((ext_vector_type(16)));

#define MFMA_ __builtin_amdgcn_mfma_f32_32x32x16_f16
#define SLOPE_ 0.2f

constexpr int kB = 64, kT = 512, kD = 8, kH = 128, kE = 96;
constexpr int kFG = 145, kTM = 510, kN = kB * kTM;   // 32640 = 510*64

// k-permutation absorbed into weight images so next-layer B-fragments are the
// held C/D quads verbatim: pi(16c+8s+j) = 32(c>>1)+16(c&1)+8(j>>2)+4s+(j&3)
__device__ __forceinline__ int pif(int k) {
  if (k >= 128) return k;
  int c = k >> 4, s = (k >> 3) & 1, j = k & 7;
  return ((c >> 1) << 5) | ((c & 1) << 4) | ((j >> 2) << 3) | (s << 2) | (j & 3);
}

__device__ __forceinline__ f16x8 gfrag(const f16* img, int f, int lane) {
  return *(const f16x8*)(img + (size_t)f*512 + lane*8);
}

// ========= weight pre-convert: f32 row-major -> f16 fragment-linear =========
template<int NF, int SK, int PERM>
__device__ __forceinline__ void cvt_img(const float* __restrict__ src,
                                        f16* __restrict__ dst, int nd,
                                        int t0, int stride) {
  const int per_d = NF * 512;
  for (int e = t0; e < nd * per_d; e += stride) {
    int dd = e / per_d, r = e - dd * per_d;
    int f = r >> 9, l = (r >> 3) & 63, j = r & 7;
    int c = f >> 2, t = f & 3;
    int row = t*32 + (l & 31);
    int col = c*16 + ((l >> 5) << 3) + j;
    if (PERM) col = pif(col);
    dst[e] = (f16)src[((size_t)dd*kH + row)*SK + col];
  }
}

__global__ __launch_bounds__(256) void cvt_kernel(
    const float* __restrict__ gW0, const float* __restrict__ gW1,
    const float* __restrict__ gW2,
    const float* __restrict__ gb0, const float* __restrict__ gb1,
    const float* __restrict__ gb2, const float* __restrict__ gWf,
    const float* __restrict__ fcW0, const float* __restrict__ fcW1,
    const float* __restrict__ fcWf,
    f16* __restrict__ W0img, f16* __restrict__ W1img, f16* __restrict__ W2img,
    f16* __restrict__ wfimg,
    f16* __restrict__ fW0img, f16* __restrict__ fW1img, f16* __restrict__ fWfimg,
    float* __restrict__ w144buf, float* __restrict__ logdet)
{
  const int stride = gridDim.x * 256;
  const int t0 = blockIdx.x*256 + threadIdx.x;

  // W0img: 40 frags/d. cols 0..127 pi(gW0), 128..144 canonical, 145 = gb0.
  for (int e = t0; e < kD*40*512; e += stride) {
    int dd = e / (40*512), r = e - dd*(40*512);
    int f = r >> 9, l = (r >> 3) & 63, j = r & 7;
    int c = f >> 2, t = f & 3;
    int row = t*32 + (l & 31);
    int col = c*16 + ((l >> 5) << 3) + j;
    float v;
    if (col < 128)       v = gW0[((size_t)dd*kH + row)*kFG + pif(col)];
    else if (col < 145)  v = gW0[((size_t)dd*kH + row)*kFG + col];
    else if (col == 145) v = gb0[dd*kH + row];
    else                 v = 0.f;
    W0img[e] = (f16)v;
  }
  // W1img/W2img: 36 frags/d. cols 0..127 pi(W), col 128 = bias, rest 0.
  for (int e = t0; e < kD*36*512; e += stride) {
    int dd = e / (36*512), r = e - dd*(36*512);
    int f = r >> 9, l = (r >> 3) & 63, j = r & 7;
    int c = f >> 2, t = f & 3;
    int row = t*32 + (l & 31);
    int col = c*16 + ((l >> 5) << 3) + j;
    float v1, v2;
    if (col < 128) {
      int pc = pif(col);
      v1 = gW1[((size_t)dd*kH + row)*kH + pc];
      v2 = gW2[((size_t)dd*kH + row)*kH + pc];
    } else if (col == 128) {
      v1 = gb1[dd*kH + row];
      v2 = gb2[dd*kH + row];
    } else { v1 = 0.f; v2 = 0.f; }
    W1img[e] = (f16)v1;
    W2img[e] = (f16)v2;
  }
  // wfimg: 8 frags/d, wf in output-row 0 only, pi-ordered cols.
  for (int e = t0; e < kD*8*512; e += stride) {
    int dd = e >> 12, r = e & 4095;
    int f = r >> 9, l = (r >> 3) & 63, j = r & 7;
    int row = l & 31;
    int col = f*16 + ((l >> 5) << 3) + j;
    wfimg[e] = (f16)((row == 0) ? gWf[dd*kH + pif(col)] : 0.f);
  }
  cvt_img<24, kE , 0>(fcW0, fW0img, 1, t0, stride);
  cvt_img<32, kH , 1>(fcW1, fW1img, 1, t0, stride);
  cvt_img<32, kH , 1>(fcWf, fWfimg, 1, t0, stride);
  for (int i = t0; i < kD*kH; i += stride)
    w144buf[i] = gW0[(size_t)i*kFG + 144];
  if (t0 < kB) logdet[t0] = 0.f;
}

// ===== fc_mlp: emb(N,96) -> embh'(N,128) f16 (pi-ordered); 1 barrier ========
__global__ __launch_bounds__(256, 2) void fc_kernel(
    const float* __restrict__ emb,
    const f16* __restrict__ fW0, const f16* __restrict__ fW1,
    const f16* __restrict__ fWf,
    const float* __restrict__ b0, const float* __restrict__ b1,
    const float* __restrict__ bf, f16* __restrict__ out)
{
  __shared__ f16 wbuf[62*512];                 // fW1 frags 0..31, fWf 0..29
  const int bn = blockIdx.x * 128;
  const int tid = threadIdx.x, wave = tid >> 6, lane = tid & 63;
  const int l31 = lane & 31, h5 = lane >> 5;
  const int n = bn + wave*32 + l31;

  #pragma unroll
  for (int i = 0; i < 8; ++i)
    *(f16x8*)(wbuf + (size_t)(tid + i*256)*8) =
        *(const f16x8*)(fW1 + (size_t)(tid + i*256)*8);
  #pragma unroll
  for (int i = 0; i < 8; ++i) {
    int idx = tid + i*256;
    if (idx < 1920)
      *(f16x8*)(wbuf + (size_t)(2048 + idx)*8) =
          *(const f16x8*)(fWf + (size_t)idx*8);
  }

  const float* erow = emb + (size_t)n*kE + h5*8;
  f16x8 eB[6];
  #pragma unroll
  for (int c = 0; c < 6; ++c) {
    float4 a = *(const float4*)(erow + c*16);
    float4 bb = *(const float4*)(erow + c*16 + 4);
    f16x8 v;
    v[0]=(f16)a.x; v[1]=(f16)a.y; v[2]=(f16)a.z; v[3]=(f16)a.w;
    v[4]=(f16)bb.x; v[5]=(f16)bb.y; v[6]=(f16)bb.z; v[7]=(f16)bb.w;
    eB[c] = v;
  }
  __syncthreads();                              // B1

  f32x16 zero = {};
  f32x16 acc[4] = {zero, zero, zero, zero};
  #pragma unroll
  for (int c = 0; c < 6; ++c)
    #pragma unroll
    for (int t = 0; t < 4; ++t)
      acc[t] = MFMA_(gfrag(fW0, c*4+t, lane), eB[c], acc[t], 0, 0, 0);

  f16x8 hq[4][2];
  #pragma unroll
  for (int t = 0; t < 4; ++t)
    #pragma unroll
    for (int q = 0; q < 4; ++q) {
      float4 b4 = *(const float4*)(b0 + t*32 + q*8 + h5*4);
      const float* bp = (const float*)&b4;
      #pragma unroll
      for (int e = 0; e < 4; ++e) {
        float z = acc[t][q*4+e] + bp[e];
        hq[t][q>>1][(q&1)*4+e] = (f16)fmaxf(z, SLOPE_*z);
      }
    }

  #pragma unroll
  for (int t = 0; t < 4; ++t) acc[t] = zero;
  #pragma unroll
  for (int c = 0; c < 8; ++c) {
    f16x8 bP = hq[c>>1][c&1];
    #pragma unroll
    for (int t = 0; t < 4; ++t)
      acc[t] = MFMA_(*(const f16x8*)(wbuf + (size_t)(c*4+t)*512 + lane*8),
                     bP, acc[t], 0, 0, 0);
  }
  #pragma unroll
  for (int t = 0; t < 4; ++t)
    #pragma unroll
    for (int q = 0; q < 4; ++q) {
      float4 b4 = *(const float4*)(b1 + t*32 + q*8 + h5*4);
      const float* bp = (const float*)&b4;
      #pragma unroll
      for (int e = 0; e < 4; ++e) {
        float z = acc[t][q*4+e] + bp[e];
        hq[t][q>>1][(q&1)*4+e] = (f16)fmaxf(z, SLOPE_*z);
      }
    }

  #pragma unroll
  for (int t = 0; t < 4; ++t) acc[t] = zero;
  #pragma unroll
  for (int c = 0; c < 8; ++c) {
    f16x8 bP = hq[c>>1][c&1];
    #pragma unroll
    for (int t = 0; t < 4; ++t) {
      int f = c*4 + t;
      f16x8 a = (f < 30) ? *(const f16x8*)(wbuf + (size_t)(32 + f)*512 + lane*8)
                         : gfrag(fWf, f, lane);
      acc[t] = MFMA_(a, bP, acc[t], 0, 0, 0);
    }
  }
  #pragma unroll
  for (int t = 0; t < 4; ++t)
    #pragma unroll
    for (int q = 0; q < 4; ++q) {
      float4 b4 = *(const float4*)(bf + t*32 + q*8 + h5*4);
      const float* bp = (const float*)&b4;
      #pragma unroll
      for (int e = 0; e < 4; ++e)
        hq[t][q>>1][(q&1)*4+e] = (f16)(acc[t][q*4+e] + bp[e]);
    }
  #pragma unroll
  for (int c = 0; c < 8; ++c)
    *(f16x8*)(out + (size_t)n*kH + c*16 + h5*8) = hq[c>>1][c&1];
}

// ==== g_mlp fwd + JVP: P/T packed into B-columns (16 primal + 16 tangent) ===
// Block = 64 rows x one d, 4 waves x 16 actual rows. One acc set (64 AGPR)
// carries both paths. Masks pass P->T as 16-bit words via shfl_xor(16).
__global__ __launch_bounds__(256, 3) void g_kernel(
    const float* __restrict__ x, const f16* __restrict__ embh,
    const f16* __restrict__ W0img, const f16* __restrict__ W1img,
    const f16* __restrict__ W2img, const f16* __restrict__ wfimg,
    const float* __restrict__ w144buf, const float* __restrict__ gbf,
    float* __restrict__ resid, float* __restrict__ logdet)
{
  __shared__ f16 wbuf[36*512];                 // W1 frags, 36 KB
  __shared__ float part[8];
  const int d = blockIdx.y, bx = blockIdx.x, bn = bx*64;
  const int tid = threadIdx.x, wave = tid >> 6, lane = tid & 63;
  const int l31 = lane & 31, h5 = lane >> 5;
  const int row = l31 & 15;                    // actual row within wave
  const bool isT = (l31 >= 16);
  const int n = bn + wave*16 + row;
  const int b = n / kTM, tt = n - b*kTM;

  const f16* W0d = W0img + (size_t)d*40*512;
  const f16* W1d = W1img + (size_t)d*36*512;
  const f16* W2d = W2img + (size_t)d*36*512;
  const f16* WFd = wfimg + (size_t)d*8*512;

  // stage W1 (2304 units)
  #pragma unroll
  for (int i = 0; i < 9; ++i)
    *(f16x8*)(wbuf + (size_t)(tid + i*256)*8) =
        *(const f16x8*)(W1d + (size_t)(tid + i*256)*8);

  // x-derived inputs (T lanes duplicate P's B so z_T == z_P at L0)
  const float* xp = x + ((size_t)b*kT + tt + h5)*kD;
  float4 xa = *(const float4*)xp;
  float4 xb = *(const float4*)(xp + 4);
  f16x8 f8;
  f8[0]=(f16)xa.x; f8[1]=(f16)xa.y; f8[2]=(f16)xa.z; f8[3]=(f16)xa.w;
  f8[4]=(f16)xb.x; f8[5]=(f16)xb.y; f8[6]=(f16)xb.z; f8[7]=(f16)xb.w;
  const float xxv = x[((size_t)b*kT + tt + 2)*kD + d];
  f16x8 zeroh = {};
  f16x8 xb9 = zeroh;                 // L0 chunk 9: [xx, 1, 0...] on h5==0
  if (!h5) { xb9[0] = (f16)xxv; xb9[1] = (f16)1.f; }
  f16x8 bC = zeroh;                  // L1/L2 bias chunk: P lanes only
  if (!h5 && !isT) bC[0] = (f16)1.f;

  f32x16 zero = {};
  f32x16 acc[4] = {zero, zero, zero, zero};

  // ---- L0 (W0 direct-global, 40 frags)
  const f16* erow = embh + (size_t)n*kH + h5*8;
  #pragma unroll
  for (int c = 0; c < 8; ++c) {
    f16x8 eF = *(const f16x8*)(erow + c*16);
    #pragma unroll
    for (int t = 0; t < 4; ++t)
      acc[t] = MFMA_(gfrag(W0d, c*4+t, lane), eF, acc[t], 0, 0, 0);
  }
  #pragma unroll
  for (int t = 0; t < 4; ++t)
    acc[t] = MFMA_(gfrag(W0d, 32+t, lane), f8, acc[t], 0, 0, 0);
  #pragma unroll
  for (int t = 0; t < 4; ++t)
    acc[t] = MFMA_(gfrag(W0d, 36+t, lane), xb9, acc[t], 0, 0, 0);

  // L0 epilogue: z local on both P and T lanes (duplicated B)
  f16x8 hq[4][2];
  #pragma unroll
  for (int t = 0; t < 4; ++t)
    #pragma unroll
    for (int q = 0; q < 4; ++q) {
      float4 w4 = *(const float4*)(w144buf + d*kH + t*32 + q*8 + h5*4);
      const float* wp = (const float*)&w4;
      #pragma unroll
      for (int e = 0; e < 4; ++e) {
        float z = acc[t][q*4+e];
        bool pos = (z >= 0.f);
        float pv = pos ? z : SLOPE_*z;
        float tv = pos ? wp[e] : SLOPE_*wp[e];
        hq[t][q>>1][(q&1)*4+e] = (f16)(isT ? tv : pv);
      }
    }
  __syncthreads();                              // B1: wbuf ready

  // ---- L1 (LDS, 9 chunks)
  #pragma unroll
  for (int t = 0; t < 4; ++t) acc[t] = zero;
  #pragma unroll
  for (int c = 0; c < 9; ++c) {
    f16x8 bF = (c < 8) ? hq[c>>1][c&1] : bC;
    #pragma unroll
    for (int t = 0; t < 4; ++t)
      acc[t] = MFMA_(*(const f16x8*)(wbuf + (size_t)(c*4+t)*512 + lane*8),
                     bF, acc[t], 0, 0, 0);
  }
  // L1 epilogue: P packs sign bits, T receives via lane^16
  #pragma unroll
  for (int t = 0; t < 4; ++t) {
    unsigned bits = 0;
    #pragma unroll
    for (int r = 0; r < 16; ++r)
      bits |= (unsigned)(acc[t][r] >= 0.f) << r;
    unsigned rb = (unsigned)__shfl_xor((int)bits, 16, 64);
    unsigned use = isT ? rb : bits;
    #pragma unroll
    for (int q = 0; q < 4; ++q)
      #pragma unroll
      for (int e = 0; e < 4; ++e) {
        float v = acc[t][q*4+e];
        hq[t][q>>1][(q&1)*4+e] =
            (f16)(((use >> (q*4+e)) & 1) ? v : SLOPE_*v);
      }
  }

  // ---- L2 (W2 direct-global, 9 chunks)
  #pragma unroll
  for (int t = 0; t < 4; ++t) acc[t] = zero;
  #pragma unroll
  for (int c = 0; c < 9; ++c) {
    f16x8 bF = (c < 8) ? hq[c>>1][c&1] : bC;
    #pragma unroll
    for (int t = 0; t < 4; ++t)
      acc[t] = MFMA_(gfrag(W2d, c*4+t, lane), bF, acc[t], 0, 0, 0);
  }
  #pragma unroll
  for (int t = 0; t < 4; ++t) {
    unsigned bits = 0;
    #pragma unroll
    for (int r = 0; r < 16; ++r)
      bits |= (unsigned)(acc[t][r] >= 0.f) << r;
    unsigned rb = (unsigned)__shfl_xor((int)bits, 16, 64);
    unsigned use = isT ? rb : bits;
    #pragma unroll
    for (int q = 0; q < 4; ++q)
      #pragma unroll
      for (int e = 0; e < 4; ++e) {
        float v = acc[t][q*4+e];
        hq[t][q>>1][(q&1)*4+e] =
            (f16)(((use >> (q*4+e)) & 1) ? v : SLOPE_*v);
      }
  }

  // ---- final dot via MFMA: P-dot on cols 0..15, T-dot on cols 16..31
  acc[0] = zero;
  #pragma unroll
  for (int c = 0; c < 8; ++c)
    acc[0] = MFMA_(gfrag(WFd, c, lane), hq[c>>1][c&1], acc[0], 0, 0, 0);

  float llog = 0.f;
  if (!h5) {
    float v = acc[0][0];
    if (!isT) resid[(size_t)n*kD + d] = v + gbf[d];
    else      llog = logf(fabsf(v));
  }
  const int bfirst = bn / kTM;
  float s0 = (b == bfirst) ? llog : 0.f;
  float s1 = llog - s0;
  #pragma unroll
  for (int off = 32; off > 0; off >>= 1) {
    s0 += __shfl_down(s0, off, 64);
    s1 += __shfl_down(s1, off, 64);
  }
  if (lane == 0) { part[wave*2] = s0; part[wave*2 + 1] = s1; }
  __syncthreads();                              // B2
  if (tid == 0) {
    float S0 = part[0] + part[2] + part[4] + part[6];
    float S1 = part[1] + part[3] + part[5] + part[7];
    atomicAdd(&logdet[bfirst], S0);
    if (S1 != 0.f) atomicAdd(&logdet[bfirst + 1], S1);
  }
}

extern "C" void kernel_launch(void* const* d_in, const int* in_sizes, int n_in,
                              void* d_out, int out_size, void* d_ws, size_t ws_size,
                              hipStream_t stream) {
  const float* x    = (const float*)d_in[0];
  const float* emb  = (const float*)d_in[1];
  const float* fcW0 = (const float*)d_in[2];
  const float* fcb0 = (const float*)d_in[3];
  const float* fcW1 = (const float*)d_in[4];
  const float* fcb1 = (const float*)d_in[5];
  const float* fcWf = (const float*)d_in[6];
  const float* fcbf = (const float*)d_in[7];
  const float* gW0  = (const float*)d_in[8];
  const float* gb0  = (const float*)d_in[9];
  const float* gW1  = (const float*)d_in[10];
  const float* gb1  = (const float*)d_in[11];
  const float* gW2  = (const float*)d_in[12];
  const float* gb2  = (const float*)d_in[13];
  const float* gWf  = (const float*)d_in[14];
  const float* gbf  = (const float*)d_in[15];
  float* out = (float*)d_out;
  float* logdet = out + (size_t)kN * kD;

  char* ws = (char*)d_ws;
  f16*   embh    = (f16*)ws;    ws += (size_t)kN*kH*2;
  f16*   W0img   = (f16*)ws;    ws += (size_t)kD*40*512*2;
  f16*   W1img   = (f16*)ws;    ws += (size_t)kD*36*512*2;
  f16*   W2img   = (f16*)ws;    ws += (size_t)kD*36*512*2;
  f16*   wfimg   = (f16*)ws;    ws += (size_t)kD*8*512*2;
  f16*   fW0img  = (f16*)ws;    ws += (size_t)24*512*2;
  f16*   fW1img  = (f16*)ws;    ws += (size_t)32*512*2;
  f16*   fWfimg  = (f16*)ws;    ws += (size_t)32*512*2;
  float* w144buf = (float*)ws;

  cvt_kernel<<<256, 256, 0, stream>>>(gW0, gW1, gW2, gb0, gb1, gb2, gWf,
                                      fcW0, fcW1, fcWf,
                                      W0img, W1img, W2img, wfimg,
                                      fW0img, fW1img, fWfimg,
                                      w144buf, logdet);
  fc_kernel<<<kN/128, 256, 0, stream>>>(emb, fW0img, fW1img, fWfimg,
                                        fcb0, fcb1, fcbf, embh);
  g_kernel<<<dim3(kN/64, kD), 256, 0, stream>>>(
      x, embh, W0img, W1img, W2img, wfimg, w144buf, gbf, out, logdet);
}